// Round 12
// baseline (526.307 us; speedup 1.0000x reference)
//
#include <hip/hip_runtime.h>

#define D 2048
#define DD ((size_t)D * (size_t)D)

typedef __attribute__((ext_vector_type(8))) short bf16x8;
typedef __attribute__((ext_vector_type(16))) float f32x16;

#define GLOBAL_AS __attribute__((address_space(1)))
#define LDS_AS __attribute__((address_space(3)))

__device__ inline unsigned short f2bf(float f) {
  unsigned u = __float_as_uint(f);
  u += 0x7fffu + ((u >> 16) & 1u);
  return (unsigned short)(u >> 16);
}

// ---------------------------------------------------------------------------
__global__ void init_vecs(const float* __restrict__ b_upper5,
                          const float* __restrict__ b_lower5,
                          const float* __restrict__ ub5,
                          const float* __restrict__ lb5,
                          float* __restrict__ bu, float* __restrict__ bl,
                          float* __restrict__ out) {
  int t = blockIdx.x * blockDim.x + threadIdx.x;
  if (t < D) {
    bu[t] = b_upper5[t];
    bl[t] = b_lower5[t];
    out[t] = ub5[t];
    out[D + t] = lb5[t];
  }
}

// ---------------------------------------------------------------------------
// prep: fused per-iteration prep pass (unchanged, proven).
//   blocks [0, 2048):   concretize row r + write bf16 copies of Wu/Wl rows
//   blocks [2048, 3072): conv_B 64x64 tile -> BsT/BdT (transposed bf16)
// ---------------------------------------------------------------------------
__global__ __launch_bounds__(256) void prep(
    const float* __restrict__ Wu, const float* __restrict__ Wl,
    const float* __restrict__ ubi, const float* __restrict__ lbi,
    const float* __restrict__ bupi, const float* __restrict__ bloi,
    float* __restrict__ bu, float* __restrict__ bl,
    float* __restrict__ best,
    unsigned short* __restrict__ oU, unsigned short* __restrict__ oL,
    const float* __restrict__ Wup, const float* __restrict__ Wlo,
    unsigned short* __restrict__ BsT, unsigned short* __restrict__ BdT,
    int update_bias, int write16) {
  __shared__ float red[4][4];
  __shared__ unsigned short sS[64][68];
  __shared__ unsigned short sD[64][68];

  const int t = threadIdx.x;

  if (blockIdx.x < 2048) {
    const int r = blockIdx.x;
    const size_t base = (size_t)r * D + t * 8;
    const int c = t * 8;

    float4 wu0 = *(const float4*)(Wu + base), wu1 = *(const float4*)(Wu + base + 4);
    float4 wl0 = *(const float4*)(Wl + base), wl1 = *(const float4*)(Wl + base + 4);
    float4 u0 = *(const float4*)(ubi + c),  u1 = *(const float4*)(ubi + c + 4);
    float4 l0 = *(const float4*)(lbi + c),  l1 = *(const float4*)(lbi + c + 4);
    float4 p0 = *(const float4*)(bupi + c), p1 = *(const float4*)(bupi + c + 4);
    float4 n0 = *(const float4*)(bloi + c), n1 = *(const float4*)(bloi + c + 4);

    float wu[8] = {wu0.x, wu0.y, wu0.z, wu0.w, wu1.x, wu1.y, wu1.z, wu1.w};
    float wl[8] = {wl0.x, wl0.y, wl0.z, wl0.w, wl1.x, wl1.y, wl1.z, wl1.w};
    float uu[8] = {u0.x, u0.y, u0.z, u0.w, u1.x, u1.y, u1.z, u1.w};
    float ll[8] = {l0.x, l0.y, l0.z, l0.w, l1.x, l1.y, l1.z, l1.w};
    float pp[8] = {p0.x, p0.y, p0.z, p0.w, p1.x, p1.y, p1.z, p1.w};
    float nn[8] = {n0.x, n0.y, n0.z, n0.w, n1.x, n1.y, n1.z, n1.w};

    float su_c = 0.f, su_b = 0.f, sl_c = 0.f, sl_b = 0.f;
    #pragma unroll
    for (int j = 0; j < 8; ++j) {
      su_c += wu[j] * (wu[j] >= 0.f ? uu[j] : ll[j]);
      su_b += wu[j] * (wu[j] >= 0.f ? pp[j] : nn[j]);
      sl_c += wl[j] * (wl[j] >= 0.f ? ll[j] : uu[j]);
      sl_b += wl[j] * (wl[j] >= 0.f ? nn[j] : pp[j]);
    }

    if (write16) {
      uint4 w;
      w.x = f2bf(wu[0]) | ((unsigned)f2bf(wu[1]) << 16);
      w.y = f2bf(wu[2]) | ((unsigned)f2bf(wu[3]) << 16);
      w.z = f2bf(wu[4]) | ((unsigned)f2bf(wu[5]) << 16);
      w.w = f2bf(wu[6]) | ((unsigned)f2bf(wu[7]) << 16);
      *(uint4*)(oU + base) = w;
      w.x = f2bf(wl[0]) | ((unsigned)f2bf(wl[1]) << 16);
      w.y = f2bf(wl[2]) | ((unsigned)f2bf(wl[3]) << 16);
      w.z = f2bf(wl[4]) | ((unsigned)f2bf(wl[5]) << 16);
      w.w = f2bf(wl[6]) | ((unsigned)f2bf(wl[7]) << 16);
      *(uint4*)(oL + base) = w;
    }

    #pragma unroll
    for (int off = 32; off; off >>= 1) {
      su_c += __shfl_down(su_c, off);
      su_b += __shfl_down(su_b, off);
      sl_c += __shfl_down(sl_c, off);
      sl_b += __shfl_down(sl_b, off);
    }
    int wave = t >> 6;
    if ((t & 63) == 0) {
      red[0][wave] = su_c; red[1][wave] = su_b;
      red[2][wave] = sl_c; red[3][wave] = sl_b;
    }
    __syncthreads();
    if (t == 0) {
      float a = red[0][0] + red[0][1] + red[0][2] + red[0][3];
      float b = red[1][0] + red[1][1] + red[1][2] + red[1][3];
      float cc = red[2][0] + red[2][1] + red[2][2] + red[2][3];
      float d = red[3][0] + red[3][1] + red[3][2] + red[3][3];
      float bu_old = bu[r], bl_old = bl[r];
      best[r]     = fminf(best[r],     a + bu_old);
      best[D + r] = fmaxf(best[D + r], cc + bl_old);
      if (update_bias) {
        bu[r] = b + bu_old;
        bl[r] = d + bl_old;
      }
    }
  } else {
    const int bx = blockIdx.x - 2048;
    const int k0 = (bx >> 5) * 64, c0 = (bx & 31) * 64;
    const int tx = t & 15, ty = t >> 4;
    #pragma unroll
    for (int r = 0; r < 4; ++r) {
      int kk = ty + r * 16;
      size_t g = (size_t)(k0 + kk) * D + c0 + tx * 4;
      float4 up = *(const float4*)(Wup + g);
      float4 lo = *(const float4*)(Wlo + g);
      sS[kk][tx * 4 + 0] = f2bf((up.x + lo.x) * 0.5f);
      sS[kk][tx * 4 + 1] = f2bf((up.y + lo.y) * 0.5f);
      sS[kk][tx * 4 + 2] = f2bf((up.z + lo.z) * 0.5f);
      sS[kk][tx * 4 + 3] = f2bf((up.w + lo.w) * 0.5f);
      sD[kk][tx * 4 + 0] = f2bf((up.x - lo.x) * 0.5f);
      sD[kk][tx * 4 + 1] = f2bf((up.y - lo.y) * 0.5f);
      sD[kk][tx * 4 + 2] = f2bf((up.z - lo.z) * 0.5f);
      sD[kk][tx * 4 + 3] = f2bf((up.w - lo.w) * 0.5f);
    }
    __syncthreads();
    #pragma unroll
    for (int r = 0; r < 4; ++r) {
      int cc = ty + r * 16;
      int kq = tx * 4;
      unsigned a0 = sS[kq + 0][cc] | ((unsigned)sS[kq + 1][cc] << 16);
      unsigned a1 = sS[kq + 2][cc] | ((unsigned)sS[kq + 3][cc] << 16);
      *(uint2*)(BsT + (size_t)(c0 + cc) * D + k0 + kq) = make_uint2(a0, a1);
      a0 = sD[kq + 0][cc] | ((unsigned)sD[kq + 1][cc] << 16);
      a1 = sD[kq + 2][cc] | ((unsigned)sD[kq + 3][cc] << 16);
      *(uint2*)(BdT + (size_t)(c0 + cc) * D + k0 + kq) = make_uint2(a0, a1);
    }
  }
}

// ---------------------------------------------------------------------------
// UNFUSED dual GEMM: one block computes ONE of {Cu, Cl} for a 128x128 tile.
//   grp==0: Cu = A @ Bs + |A| @ Bd     (A = w16U)
//   grp==1: Cl = A @ Bs - |A| @ Bd     (A = w16L)
// grid 512 x 256 threads -> 2 independent blocks per CU (two barrier
// domains; one block's MFMA hides the sibling's staging/drain bubble).
// BK=32, 3 LDS streams (A|Bs|Bd, [128 rows][32 k] bf16), dbuf 2x24KB.
// R8-style schedule: STAGE(next) -> compute -> __syncthreads.
// Swizzle f(row)=(row>>1)&3 on stage-source and read (R10-verified, 4-way).
// Block decode: XCD x = bid&7, j = bid>>3; grp = j&1; tile = x*32 + (j>>1)
// -> Cu/Cl pair of a tile lands on the SAME XCD (shared B in that L2).
// ---------------------------------------------------------------------------
__global__ __launch_bounds__(256, 2) void gemm_half(
    const unsigned short* __restrict__ w16U,
    const unsigned short* __restrict__ w16L,
    const unsigned short* __restrict__ BsT,
    const unsigned short* __restrict__ BdT,
    float* __restrict__ Cu, float* __restrict__ Cl) {
  extern __shared__ unsigned char lds[];

  const int bid = blockIdx.x;
  const int x = bid & 7, j = bid >> 3;
  const int grp = j & 1;
  const int tile = x * 32 + (j >> 1);            // 0..255
  const int row0 = (tile >> 4) * 128, col0 = (tile & 15) * 128;

  const int tid = threadIdx.x;
  const int lane = tid & 63, wid = tid >> 6;     // 4 waves
  const int wr = wid >> 1, wc = wid & 1;         // 2x2 -> 64x64 per wave
  const int l31 = lane & 31, kh = lane >> 5;

  const unsigned short* Aown = grp ? w16L : w16U;

  // staging: per stream tile = [128 rows][32 k] = 8KB = 8 chunks of 1KB
  // (16 rows x 64B). wave wid stages chunks {wid, wid+4} of each stream.
  int rowc[2], swel[2];
  #pragma unroll
  for (int c = 0; c < 2; ++c) {
    rowc[c] = (wid + c * 4) * 16 + (lane >> 2);
    swel[c] = ((lane & 3) ^ ((rowc[c] >> 1) & 3)) * 8;   // pre-swizzled source
  }
  const unsigned short* gA[2]; const unsigned short* gBs[2];
  const unsigned short* gBd[2];
  #pragma unroll
  for (int c = 0; c < 2; ++c) {
    gA[c]  = Aown + (size_t)(row0 + rowc[c]) * D + swel[c];
    gBs[c] = BsT + (size_t)(col0 + rowc[c]) * D + swel[c];
    gBd[c] = BdT + (size_t)(col0 + rowc[c]) * D + swel[c];
  }

  f32x16 acc[2][2] = {};

  // fragment byte offsets within a stream (row*64B, slot=(ks*2+kh)^f(row))
  int aoff[2][2], boff[2][2];
  #pragma unroll
  for (int mb = 0; mb < 2; ++mb) {
    int ar = wr * 64 + mb * 32 + l31;
    #pragma unroll
    for (int ks = 0; ks < 2; ++ks)
      aoff[mb][ks] = ar * 64 + (((ks * 2 + kh) ^ ((ar >> 1) & 3)) * 16);
  }
  #pragma unroll
  for (int nb = 0; nb < 2; ++nb) {
    int bc = wc * 64 + nb * 32 + l31;
    #pragma unroll
    for (int ks = 0; ks < 2; ++ks)
      boff[nb][ks] = bc * 64 + (((ks * 2 + kh) ^ ((bc >> 1) & 3)) * 16);
  }

  // buffer layout: [buf 0/1: 24KB = A 8KB | Bs 8KB | Bd 8KB]
  #define STAGE(buf, kt)                                                          \
    do {                                                                          \
      _Pragma("unroll")                                                           \
      for (int c = 0; c < 2; ++c) {                                               \
        unsigned dst = (unsigned)(buf) * 24576u + (unsigned)(wid + c * 4) * 1024u;\
        __builtin_amdgcn_global_load_lds((const GLOBAL_AS unsigned*)(gA[c] + (kt)),\
            (LDS_AS unsigned*)(lds + 0 + dst), 16, 0, 0);                         \
        __builtin_amdgcn_global_load_lds((const GLOBAL_AS unsigned*)(gBs[c] + (kt)),\
            (LDS_AS unsigned*)(lds + 8192 + dst), 16, 0, 0);                      \
        __builtin_amdgcn_global_load_lds((const GLOBAL_AS unsigned*)(gBd[c] + (kt)),\
            (LDS_AS unsigned*)(lds + 16384 + dst), 16, 0, 0);                     \
      }                                                                           \
    } while (0)

  STAGE(0, 0);
  __syncthreads();

  int buf = 0;
  for (int t = 0; t < 64; ++t) {
    if (t < 63) STAGE(buf ^ 1, (t + 1) * 32);

    const unsigned char* Ab = lds + (unsigned)buf * 24576u;
    const unsigned char* Sb = Ab + 8192;
    const unsigned char* Db = Ab + 16384;

    #pragma unroll
    for (int ks = 0; ks < 2; ++ks) {
      bf16x8 aw0 = *(const bf16x8*)(Ab + aoff[0][ks]);
      bf16x8 aw1 = *(const bf16x8*)(Ab + aoff[1][ks]);
      bf16x8 bs0 = *(const bf16x8*)(Sb + boff[0][ks]);
      bf16x8 bs1 = *(const bf16x8*)(Sb + boff[1][ks]);
      bf16x8 bd0 = *(const bf16x8*)(Db + boff[0][ks]);
      bf16x8 bd1 = *(const bf16x8*)(Db + boff[1][ks]);
      if (grp) { bd0 ^= (short)0x8000; bd1 ^= (short)0x8000; }
      bf16x8 av0 = aw0 & (short)0x7fff;
      bf16x8 av1 = aw1 & (short)0x7fff;

      acc[0][0] = __builtin_amdgcn_mfma_f32_32x32x16_bf16(aw0, bs0, acc[0][0], 0, 0, 0);
      acc[0][0] = __builtin_amdgcn_mfma_f32_32x32x16_bf16(av0, bd0, acc[0][0], 0, 0, 0);
      acc[0][1] = __builtin_amdgcn_mfma_f32_32x32x16_bf16(aw0, bs1, acc[0][1], 0, 0, 0);
      acc[0][1] = __builtin_amdgcn_mfma_f32_32x32x16_bf16(av0, bd1, acc[0][1], 0, 0, 0);
      acc[1][0] = __builtin_amdgcn_mfma_f32_32x32x16_bf16(aw1, bs0, acc[1][0], 0, 0, 0);
      acc[1][0] = __builtin_amdgcn_mfma_f32_32x32x16_bf16(av1, bd0, acc[1][0], 0, 0, 0);
      acc[1][1] = __builtin_amdgcn_mfma_f32_32x32x16_bf16(aw1, bs1, acc[1][1], 0, 0, 0);
      acc[1][1] = __builtin_amdgcn_mfma_f32_32x32x16_bf16(av1, bd1, acc[1][1], 0, 0, 0);
    }

    __syncthreads();
    buf ^= 1;
  }
  #undef STAGE

  // epilogue: C/D layout col=lane&31, row=(reg&3)+8*(reg>>2)+4*(lane>>5)
  float* C = grp ? Cl : Cu;
  #pragma unroll
  for (int mb = 0; mb < 2; ++mb)
    #pragma unroll
    for (int nb = 0; nb < 2; ++nb) {
      const int colg = col0 + wc * 64 + nb * 32 + l31;
      const int rowb = row0 + wr * 64 + mb * 32 + kh * 4;
      #pragma unroll
      for (int g = 0; g < 4; ++g)
        #pragma unroll
        for (int j2 = 0; j2 < 4; ++j2)
          C[(size_t)(rowb + g * 8 + j2) * D + colg] = acc[mb][nb][g * 4 + j2];
    }
}

// ---------------------------------------------------------------------------
extern "C" void kernel_launch(void* const* d_in, const int* in_sizes, int n_in,
                              void* d_out, int out_size, void* d_ws, size_t ws_size,
                              hipStream_t stream) {
  const float* W_upper = (const float*)d_in[0];
  const float* W_lower = (const float*)d_in[1];
  const float* b_upper = (const float*)d_in[2];
  const float* b_lower = (const float*)d_in[3];
  const float* ub      = (const float*)d_in[4];
  const float* lb      = (const float*)d_in[5];
  float* out = (float*)d_out;
  float* ws  = (float*)d_ws;

  float* curU = ws;                                       // DD f32
  float* curL = ws + DD;                                  // DD f32
  unsigned short* w16U = (unsigned short*)(ws + 2 * DD);  // DD bf16
  unsigned short* w16L = w16U + DD;
  unsigned short* BsT  = w16L + DD;
  unsigned short* BdT  = BsT + DD;
  float* bu = (float*)(BdT + DD);                         // D f32
  float* bl = bu + D;

  static_cast<void>(hipFuncSetAttribute(
      (const void*)gemm_half, hipFuncAttributeMaxDynamicSharedMemorySize, 49152));

  init_vecs<<<(D + 255) / 256, 256, 0, stream>>>(
      b_upper + 5 * D, b_lower + 5 * D, ub + 5 * D, lb + 5 * D, bu, bl, out);

  const float* cU = W_upper + 5 * DD;
  const float* cL = W_lower + 5 * DD;
  for (int i = 4; i >= 0; --i) {
    prep<<<3072, 256, 0, stream>>>(cU, cL, ub + (size_t)i * D, lb + (size_t)i * D,
                                   b_upper + (size_t)i * D, b_lower + (size_t)i * D,
                                   bu, bl, out, w16U, w16L,
                                   W_upper + (size_t)i * DD, W_lower + (size_t)i * DD,
                                   BsT, BdT, 1, 1);
    gemm_half<<<512, 256, 49152, stream>>>(w16U, w16L, BsT, BdT, curU, curL);
    cU = curU; cL = curL;
  }
  prep<<<2048, 256, 0, stream>>>(cU, cL, ub, lb, b_upper, b_lower,
                                 bu, bl, out, w16U, w16L,
                                 (const float*)nullptr, (const float*)nullptr,
                                 (unsigned short*)nullptr, (unsigned short*)nullptr,
                                 0, 0);
}

// Round 13
// 439.196 us; speedup vs baseline: 1.1983x; 1.1983x over previous
//
#include <hip/hip_runtime.h>

#define D 2048
#define DD ((size_t)D * (size_t)D)

typedef __attribute__((ext_vector_type(8))) short bf16x8;
typedef __attribute__((ext_vector_type(16))) float f32x16;

#define GLOBAL_AS __attribute__((address_space(1)))
#define LDS_AS __attribute__((address_space(3)))

__device__ inline unsigned short f2bf(float f) {
  unsigned u = __float_as_uint(f);
  u += 0x7fffu + ((u >> 16) & 1u);
  return (unsigned short)(u >> 16);
}
__device__ inline float bf2f(unsigned us) {
  return __uint_as_float(us << 16);
}

// ---------------------------------------------------------------------------
__global__ void init_vecs(const float* __restrict__ b_upper5,
                          const float* __restrict__ b_lower5,
                          const float* __restrict__ ub5,
                          const float* __restrict__ lb5,
                          float* __restrict__ bu, float* __restrict__ bl,
                          float* __restrict__ out) {
  int t = blockIdx.x * blockDim.x + threadIdx.x;
  if (t < D) {
    bu[t] = b_upper5[t];
    bl[t] = b_lower5[t];
    out[t] = ub5[t];
    out[D + t] = lb5[t];
  }
}

// ---------------------------------------------------------------------------
// prep: fused per-iteration prep pass.
//   blocks [0, 2048):   concretize row r (+ on first call: convert f32 W
//                       rows to bf16 into oU/oL — the chain is bf16 after)
//   blocks [2048, 3072): conv_B 64x64 tile -> BsT/BdT (transposed bf16)
// ---------------------------------------------------------------------------
__global__ __launch_bounds__(256) void prep(
    const float* __restrict__ Wu32, const float* __restrict__ Wl32,
    const unsigned short* __restrict__ WuA, const unsigned short* __restrict__ WlA,
    const float* __restrict__ ubi, const float* __restrict__ lbi,
    const float* __restrict__ bupi, const float* __restrict__ bloi,
    float* __restrict__ bu, float* __restrict__ bl,
    float* __restrict__ best,
    unsigned short* __restrict__ oU, unsigned short* __restrict__ oL,
    const float* __restrict__ Wup, const float* __restrict__ Wlo,
    unsigned short* __restrict__ BsT, unsigned short* __restrict__ BdT,
    int update_bias, int first) {
  __shared__ float red[4][4];
  __shared__ unsigned short sS[64][68];
  __shared__ unsigned short sD[64][68];

  const int t = threadIdx.x;

  if (blockIdx.x < 2048) {
    const int r = blockIdx.x;
    const size_t base = (size_t)r * D + t * 8;
    const int c = t * 8;

    float wu[8], wl[8];
    if (first) {
      float4 wu0 = *(const float4*)(Wu32 + base), wu1 = *(const float4*)(Wu32 + base + 4);
      float4 wl0 = *(const float4*)(Wl32 + base), wl1 = *(const float4*)(Wl32 + base + 4);
      wu[0] = wu0.x; wu[1] = wu0.y; wu[2] = wu0.z; wu[3] = wu0.w;
      wu[4] = wu1.x; wu[5] = wu1.y; wu[6] = wu1.z; wu[7] = wu1.w;
      wl[0] = wl0.x; wl[1] = wl0.y; wl[2] = wl0.z; wl[3] = wl0.w;
      wl[4] = wl1.x; wl[5] = wl1.y; wl[6] = wl1.z; wl[7] = wl1.w;
      uint4 w;
      w.x = f2bf(wu[0]) | ((unsigned)f2bf(wu[1]) << 16);
      w.y = f2bf(wu[2]) | ((unsigned)f2bf(wu[3]) << 16);
      w.z = f2bf(wu[4]) | ((unsigned)f2bf(wu[5]) << 16);
      w.w = f2bf(wu[6]) | ((unsigned)f2bf(wu[7]) << 16);
      *(uint4*)(oU + base) = w;
      w.x = f2bf(wl[0]) | ((unsigned)f2bf(wl[1]) << 16);
      w.y = f2bf(wl[2]) | ((unsigned)f2bf(wl[3]) << 16);
      w.z = f2bf(wl[4]) | ((unsigned)f2bf(wl[5]) << 16);
      w.w = f2bf(wl[6]) | ((unsigned)f2bf(wl[7]) << 16);
      *(uint4*)(oL + base) = w;
    } else {
      uint4 a = *(const uint4*)(WuA + base);
      uint4 b = *(const uint4*)(WlA + base);
      wu[0] = bf2f(a.x & 0xffffu); wu[1] = bf2f(a.x >> 16);
      wu[2] = bf2f(a.y & 0xffffu); wu[3] = bf2f(a.y >> 16);
      wu[4] = bf2f(a.z & 0xffffu); wu[5] = bf2f(a.z >> 16);
      wu[6] = bf2f(a.w & 0xffffu); wu[7] = bf2f(a.w >> 16);
      wl[0] = bf2f(b.x & 0xffffu); wl[1] = bf2f(b.x >> 16);
      wl[2] = bf2f(b.y & 0xffffu); wl[3] = bf2f(b.y >> 16);
      wl[4] = bf2f(b.z & 0xffffu); wl[5] = bf2f(b.z >> 16);
      wl[6] = bf2f(b.w & 0xffffu); wl[7] = bf2f(b.w >> 16);
    }

    float4 u0 = *(const float4*)(ubi + c),  u1 = *(const float4*)(ubi + c + 4);
    float4 l0 = *(const float4*)(lbi + c),  l1 = *(const float4*)(lbi + c + 4);
    float4 p0 = *(const float4*)(bupi + c), p1 = *(const float4*)(bupi + c + 4);
    float4 n0 = *(const float4*)(bloi + c), n1 = *(const float4*)(bloi + c + 4);
    float uu[8] = {u0.x, u0.y, u0.z, u0.w, u1.x, u1.y, u1.z, u1.w};
    float ll[8] = {l0.x, l0.y, l0.z, l0.w, l1.x, l1.y, l1.z, l1.w};
    float pp[8] = {p0.x, p0.y, p0.z, p0.w, p1.x, p1.y, p1.z, p1.w};
    float nn[8] = {n0.x, n0.y, n0.z, n0.w, n1.x, n1.y, n1.z, n1.w};

    float su_c = 0.f, su_b = 0.f, sl_c = 0.f, sl_b = 0.f;
    #pragma unroll
    for (int j = 0; j < 8; ++j) {
      su_c += wu[j] * (wu[j] >= 0.f ? uu[j] : ll[j]);
      su_b += wu[j] * (wu[j] >= 0.f ? pp[j] : nn[j]);
      sl_c += wl[j] * (wl[j] >= 0.f ? ll[j] : uu[j]);
      sl_b += wl[j] * (wl[j] >= 0.f ? nn[j] : pp[j]);
    }

    #pragma unroll
    for (int off = 32; off; off >>= 1) {
      su_c += __shfl_down(su_c, off);
      su_b += __shfl_down(su_b, off);
      sl_c += __shfl_down(sl_c, off);
      sl_b += __shfl_down(sl_b, off);
    }
    int wave = t >> 6;
    if ((t & 63) == 0) {
      red[0][wave] = su_c; red[1][wave] = su_b;
      red[2][wave] = sl_c; red[3][wave] = sl_b;
    }
    __syncthreads();
    if (t == 0) {
      float a = red[0][0] + red[0][1] + red[0][2] + red[0][3];
      float b = red[1][0] + red[1][1] + red[1][2] + red[1][3];
      float cc = red[2][0] + red[2][1] + red[2][2] + red[2][3];
      float d = red[3][0] + red[3][1] + red[3][2] + red[3][3];
      float bu_old = bu[r], bl_old = bl[r];
      best[r]     = fminf(best[r],     a + bu_old);
      best[D + r] = fmaxf(best[D + r], cc + bl_old);
      if (update_bias) {
        bu[r] = b + bu_old;
        bl[r] = d + bl_old;
      }
    }
  } else {
    const int bx = blockIdx.x - 2048;
    const int k0 = (bx >> 5) * 64, c0 = (bx & 31) * 64;
    const int tx = t & 15, ty = t >> 4;
    #pragma unroll
    for (int r = 0; r < 4; ++r) {
      int kk = ty + r * 16;
      size_t g = (size_t)(k0 + kk) * D + c0 + tx * 4;
      float4 up = *(const float4*)(Wup + g);
      float4 lo = *(const float4*)(Wlo + g);
      sS[kk][tx * 4 + 0] = f2bf((up.x + lo.x) * 0.5f);
      sS[kk][tx * 4 + 1] = f2bf((up.y + lo.y) * 0.5f);
      sS[kk][tx * 4 + 2] = f2bf((up.z + lo.z) * 0.5f);
      sS[kk][tx * 4 + 3] = f2bf((up.w + lo.w) * 0.5f);
      sD[kk][tx * 4 + 0] = f2bf((up.x - lo.x) * 0.5f);
      sD[kk][tx * 4 + 1] = f2bf((up.y - lo.y) * 0.5f);
      sD[kk][tx * 4 + 2] = f2bf((up.z - lo.z) * 0.5f);
      sD[kk][tx * 4 + 3] = f2bf((up.w - lo.w) * 0.5f);
    }
    __syncthreads();
    #pragma unroll
    for (int r = 0; r < 4; ++r) {
      int cc = ty + r * 16;
      int kq = tx * 4;
      unsigned a0 = sS[kq + 0][cc] | ((unsigned)sS[kq + 1][cc] << 16);
      unsigned a1 = sS[kq + 2][cc] | ((unsigned)sS[kq + 3][cc] << 16);
      *(uint2*)(BsT + (size_t)(c0 + cc) * D + k0 + kq) = make_uint2(a0, a1);
      a0 = sD[kq + 0][cc] | ((unsigned)sD[kq + 1][cc] << 16);
      a1 = sD[kq + 2][cc] | ((unsigned)sD[kq + 3][cc] << 16);
      *(uint2*)(BdT + (size_t)(c0 + cc) * D + k0 + kq) = make_uint2(a0, a1);
    }
  }
}

// ---------------------------------------------------------------------------
// Fused dual GEMM — R8 structure verbatim (the measured optimum), bf16 out.
//   waves 0-3: Cu16 = A @ Bs + |A| @ Bd   (A = w16U)
//   waves 4-7: Cl16 = A @ Bs - |A| @ Bd   (A = w16L)
// BK=64, 2 phases, dynamic LDS 128KB (4 streams x 16KB x dbuf), grid 256.
// Stream tile [128 rows][64 k] bf16; 8 x 16B slots/row; swizzle
// slot ^= (row & 7) on BOTH stage-source and read (involution, 4-way floor).
// XCD-aware block swizzle (bijective, 256 % 8 == 0).
// ---------------------------------------------------------------------------
__global__ __launch_bounds__(512, 2) void gemm_fused(
    const unsigned short* __restrict__ w16U,
    const unsigned short* __restrict__ w16L,
    const unsigned short* __restrict__ BsT,
    const unsigned short* __restrict__ BdT,
    unsigned short* __restrict__ Cu, unsigned short* __restrict__ Cl) {
  extern __shared__ unsigned char lds[];

  const int bid = blockIdx.x;
  const int vid = (bid & 7) * 32 + (bid >> 3);
  const int row0 = (vid >> 4) * 128, col0 = (vid & 15) * 128;

  const int tid = threadIdx.x;
  const int lane = tid & 63, wid = tid >> 6;
  const int grp = wid >> 2;            // 0 = upper path, 1 = lower path
  const int w2 = wid & 3;
  const int wr = w2 >> 1, wc = w2 & 1; // 64x64 sub-tile coords
  const int l31 = lane & 31, kh = lane >> 5;

  // staging: stream tile = 16KB = 16 chunks of 1KB (8 rows x 128B).
  // wave wid stages chunks {wid, wid+8}. lane l -> row_in_chunk l>>3, slot l&7.
  const int srow8 = lane >> 3;
  const int slot  = lane & 7;
  int rowc[2], swel[2];
  #pragma unroll
  for (int c = 0; c < 2; ++c) {
    rowc[c] = (wid + c * 8) * 8 + srow8;
    swel[c] = (slot ^ (rowc[c] & 7)) * 8;      // pre-swizzled source elem offset
  }
  const unsigned short* gAU[2]; const unsigned short* gAL[2];
  const unsigned short* gBs[2]; const unsigned short* gBd[2];
  #pragma unroll
  for (int c = 0; c < 2; ++c) {
    gAU[c] = w16U + (size_t)(row0 + rowc[c]) * D + swel[c];
    gAL[c] = w16L + (size_t)(row0 + rowc[c]) * D + swel[c];
    gBs[c] = BsT + (size_t)(col0 + rowc[c]) * D + swel[c];
    gBd[c] = BdT + (size_t)(col0 + rowc[c]) * D + swel[c];
  }

  f32x16 acc[2][2] = {};

  // fragment LDS byte offsets within a stream (row*128, slot = (ks*2+kh)^(row&7))
  int aoff[2][4], boff[2][4];
  #pragma unroll
  for (int mb = 0; mb < 2; ++mb) {
    int ar = wr * 64 + mb * 32 + l31;
    #pragma unroll
    for (int ks = 0; ks < 4; ++ks)
      aoff[mb][ks] = ar * 128 + (((ks * 2 + kh) ^ (ar & 7)) * 16);
  }
  #pragma unroll
  for (int nb = 0; nb < 2; ++nb) {
    int bc = wc * 64 + nb * 32 + l31;
    #pragma unroll
    for (int ks = 0; ks < 4; ++ks)
      boff[nb][ks] = bc * 128 + (((ks * 2 + kh) ^ (bc & 7)) * 16);
  }

  #define STAGE(curb, kt)                                                          \
    do {                                                                           \
      unsigned bb = (unsigned)(curb) * 65536u;                                     \
      _Pragma("unroll")                                                            \
      for (int c = 0; c < 2; ++c) {                                                \
        unsigned dst = bb + (unsigned)(wid + c * 8) * 1024u;                       \
        __builtin_amdgcn_global_load_lds((const GLOBAL_AS unsigned*)(gAU[c] + (kt)),\
            (LDS_AS unsigned*)(lds + 0 + dst), 16, 0, 0);                          \
        __builtin_amdgcn_global_load_lds((const GLOBAL_AS unsigned*)(gAL[c] + (kt)),\
            (LDS_AS unsigned*)(lds + 16384 + dst), 16, 0, 0);                      \
        __builtin_amdgcn_global_load_lds((const GLOBAL_AS unsigned*)(gBs[c] + (kt)),\
            (LDS_AS unsigned*)(lds + 32768 + dst), 16, 0, 0);                      \
        __builtin_amdgcn_global_load_lds((const GLOBAL_AS unsigned*)(gBd[c] + (kt)),\
            (LDS_AS unsigned*)(lds + 49152 + dst), 16, 0, 0);                      \
      }                                                                            \
    } while (0)

  STAGE(0, 0);
  __syncthreads();

  int cur = 0;
  const unsigned Abase = grp ? 16384u : 0u;
  for (int t = 0; t < 32; ++t) {
    if (t < 31) STAGE(cur ^ 1, (t + 1) * 64);

    const unsigned char* Ab = lds + Abase + cur * 65536;
    const unsigned char* Sb = lds + 32768 + cur * 65536;
    const unsigned char* Db = lds + 49152 + cur * 65536;

    #pragma unroll
    for (int ks = 0; ks < 4; ++ks) {
      bf16x8 aw0 = *(const bf16x8*)(Ab + aoff[0][ks]);
      bf16x8 aw1 = *(const bf16x8*)(Ab + aoff[1][ks]);
      bf16x8 bs0 = *(const bf16x8*)(Sb + boff[0][ks]);
      bf16x8 bs1 = *(const bf16x8*)(Sb + boff[1][ks]);
      bf16x8 bd0 = *(const bf16x8*)(Db + boff[0][ks]);
      bf16x8 bd1 = *(const bf16x8*)(Db + boff[1][ks]);
      if (grp) { bd0 ^= (short)0x8000; bd1 ^= (short)0x8000; }
      bf16x8 av0 = aw0 & (short)0x7fff;
      bf16x8 av1 = aw1 & (short)0x7fff;

      acc[0][0] = __builtin_amdgcn_mfma_f32_32x32x16_bf16(aw0, bs0, acc[0][0], 0, 0, 0);
      acc[0][0] = __builtin_amdgcn_mfma_f32_32x32x16_bf16(av0, bd0, acc[0][0], 0, 0, 0);
      acc[0][1] = __builtin_amdgcn_mfma_f32_32x32x16_bf16(aw0, bs1, acc[0][1], 0, 0, 0);
      acc[0][1] = __builtin_amdgcn_mfma_f32_32x32x16_bf16(av0, bd1, acc[0][1], 0, 0, 0);
      acc[1][0] = __builtin_amdgcn_mfma_f32_32x32x16_bf16(aw1, bs0, acc[1][0], 0, 0, 0);
      acc[1][0] = __builtin_amdgcn_mfma_f32_32x32x16_bf16(av1, bd0, acc[1][0], 0, 0, 0);
      acc[1][1] = __builtin_amdgcn_mfma_f32_32x32x16_bf16(aw1, bs1, acc[1][1], 0, 0, 0);
      acc[1][1] = __builtin_amdgcn_mfma_f32_32x32x16_bf16(av1, bd1, acc[1][1], 0, 0, 0);
    }

    __syncthreads();
    cur ^= 1;
  }
  #undef STAGE

  // epilogue (bf16): C/D layout col=lane&31, row=(reg&3)+8*(reg>>2)+4*(lane>>5)
  unsigned short* C = grp ? Cl : Cu;
  #pragma unroll
  for (int mb = 0; mb < 2; ++mb)
    #pragma unroll
    for (int nb = 0; nb < 2; ++nb) {
      const int colg = col0 + wc * 64 + nb * 32 + l31;
      const int rowb = row0 + wr * 64 + mb * 32 + kh * 4;
      #pragma unroll
      for (int g = 0; g < 4; ++g)
        #pragma unroll
        for (int j = 0; j < 4; ++j)
          C[(size_t)(rowb + g * 8 + j) * D + colg] = f2bf(acc[mb][nb][g * 4 + j]);
    }
}

// ---------------------------------------------------------------------------
extern "C" void kernel_launch(void* const* d_in, const int* in_sizes, int n_in,
                              void* d_out, int out_size, void* d_ws, size_t ws_size,
                              hipStream_t stream) {
  const float* W_upper = (const float*)d_in[0];
  const float* W_lower = (const float*)d_in[1];
  const float* b_upper = (const float*)d_in[2];
  const float* b_lower = (const float*)d_in[3];
  const float* ub      = (const float*)d_in[4];
  const float* lb      = (const float*)d_in[5];
  float* out = (float*)d_out;

  // workspace (48MB + 16KB): bf16 A ping-pong pairs, BsT/BdT, bias vecs
  unsigned short* aU[2]; unsigned short* aL[2];
  aU[0] = (unsigned short*)d_ws;
  aL[0] = aU[0] + DD;
  aU[1] = aL[0] + DD;
  aL[1] = aU[1] + DD;
  unsigned short* BsT = aL[1] + DD;
  unsigned short* BdT = BsT + DD;
  float* bu = (float*)(BdT + DD);
  float* bl = bu + D;

  static_cast<void>(hipFuncSetAttribute(
      (const void*)gemm_fused, hipFuncAttributeMaxDynamicSharedMemorySize, 131072));

  init_vecs<<<(D + 255) / 256, 256, 0, stream>>>(
      b_upper + 5 * D, b_lower + 5 * D, ub + 5 * D, lb + 5 * D, bu, bl, out);

  int cur = 0;
  for (int i = 4; i >= 0; --i) {
    const int first = (i == 4);
    prep<<<3072, 256, 0, stream>>>(
        W_upper + 5 * DD, W_lower + 5 * DD,          // f32 A (used when first)
        aU[cur], aL[cur],                             // bf16 A (used when !first)
        ub + (size_t)i * D, lb + (size_t)i * D,
        b_upper + (size_t)i * D, b_lower + (size_t)i * D,
        bu, bl, out,
        aU[cur], aL[cur],                             // bf16 A out (first only)
        W_upper + (size_t)i * DD, W_lower + (size_t)i * DD,
        BsT, BdT, 1, first);
    gemm_fused<<<256, 512, 131072, stream>>>(aU[cur], aL[cur], BsT, BdT,
                                             aU[cur ^ 1], aL[cur ^ 1]);
    cur ^= 1;
  }
  // final concretization against input-layer bounds (layer 0)
  prep<<<2048, 256, 0, stream>>>(
      (const float*)nullptr, (const float*)nullptr,
      aU[cur], aL[cur],
      ub, lb, b_upper, b_lower, bu, bl, out,
      (unsigned short*)nullptr, (unsigned short*)nullptr,
      (const float*)nullptr, (const float*)nullptr,
      (unsigned short*)nullptr, (unsigned short*)nullptr, 0, 0);
}

// Round 15
// 422.274 us; speedup vs baseline: 1.2464x; 1.0401x over previous
//
#include <hip/hip_runtime.h>

#define D 2048
#define DD ((size_t)D * (size_t)D)

typedef __attribute__((ext_vector_type(8))) short bf16x8;
typedef __attribute__((ext_vector_type(16))) float f32x16;

#define GLOBAL_AS __attribute__((address_space(1)))
#define LDS_AS __attribute__((address_space(3)))

__device__ inline unsigned short f2bf(float f) {
  unsigned u = __float_as_uint(f);
  u += 0x7fffu + ((u >> 16) & 1u);
  return (unsigned short)(u >> 16);
}
__device__ inline float bf2f(unsigned us) {
  return __uint_as_float(us << 16);
}

// ---------------------------------------------------------------------------
__global__ void init_vecs(const float* __restrict__ b_upper5,
                          const float* __restrict__ b_lower5,
                          const float* __restrict__ ub5,
                          const float* __restrict__ lb5,
                          float* __restrict__ bu, float* __restrict__ bl,
                          float* __restrict__ out) {
  int t = blockIdx.x * blockDim.x + threadIdx.x;
  if (t < D) {
    bu[t] = b_upper5[t];
    bl[t] = b_lower5[t];
    out[t] = ub5[t];
    out[D + t] = lb5[t];
  }
}

// ---------------------------------------------------------------------------
// prep: fused per-iteration prep pass (unchanged from R13, proven).
//   blocks [0, 2048):   concretize row r (+ first call: f32 W -> bf16 A)
//   blocks [2048, 3072): conv_B 64x64 tile -> BsT/BdT (transposed bf16)
// ---------------------------------------------------------------------------
__global__ __launch_bounds__(256) void prep(
    const float* __restrict__ Wu32, const float* __restrict__ Wl32,
    const unsigned short* __restrict__ WuA, const unsigned short* __restrict__ WlA,
    const float* __restrict__ ubi, const float* __restrict__ lbi,
    const float* __restrict__ bupi, const float* __restrict__ bloi,
    float* __restrict__ bu, float* __restrict__ bl,
    float* __restrict__ best,
    unsigned short* __restrict__ oU, unsigned short* __restrict__ oL,
    const float* __restrict__ Wup, const float* __restrict__ Wlo,
    unsigned short* __restrict__ BsT, unsigned short* __restrict__ BdT,
    int update_bias, int first) {
  __shared__ float red[4][4];
  __shared__ unsigned short sS[64][68];
  __shared__ unsigned short sD[64][68];

  const int t = threadIdx.x;

  if (blockIdx.x < 2048) {
    const int r = blockIdx.x;
    const size_t base = (size_t)r * D + t * 8;
    const int c = t * 8;

    float wu[8], wl[8];
    if (first) {
      float4 wu0 = *(const float4*)(Wu32 + base), wu1 = *(const float4*)(Wu32 + base + 4);
      float4 wl0 = *(const float4*)(Wl32 + base), wl1 = *(const float4*)(Wl32 + base + 4);
      wu[0] = wu0.x; wu[1] = wu0.y; wu[2] = wu0.z; wu[3] = wu0.w;
      wu[4] = wu1.x; wu[5] = wu1.y; wu[6] = wu1.z; wu[7] = wu1.w;
      wl[0] = wl0.x; wl[1] = wl0.y; wl[2] = wl0.z; wl[3] = wl0.w;
      wl[4] = wl1.x; wl[5] = wl1.y; wl[6] = wl1.z; wl[7] = wl1.w;
      uint4 w;
      w.x = f2bf(wu[0]) | ((unsigned)f2bf(wu[1]) << 16);
      w.y = f2bf(wu[2]) | ((unsigned)f2bf(wu[3]) << 16);
      w.z = f2bf(wu[4]) | ((unsigned)f2bf(wu[5]) << 16);
      w.w = f2bf(wu[6]) | ((unsigned)f2bf(wu[7]) << 16);
      *(uint4*)(oU + base) = w;
      w.x = f2bf(wl[0]) | ((unsigned)f2bf(wl[1]) << 16);
      w.y = f2bf(wl[2]) | ((unsigned)f2bf(wl[3]) << 16);
      w.z = f2bf(wl[4]) | ((unsigned)f2bf(wl[5]) << 16);
      w.w = f2bf(wl[6]) | ((unsigned)f2bf(wl[7]) << 16);
      *(uint4*)(oL + base) = w;
    } else {
      uint4 a = *(const uint4*)(WuA + base);
      uint4 b = *(const uint4*)(WlA + base);
      wu[0] = bf2f(a.x & 0xffffu); wu[1] = bf2f(a.x >> 16);
      wu[2] = bf2f(a.y & 0xffffu); wu[3] = bf2f(a.y >> 16);
      wu[4] = bf2f(a.z & 0xffffu); wu[5] = bf2f(a.z >> 16);
      wu[6] = bf2f(a.w & 0xffffu); wu[7] = bf2f(a.w >> 16);
      wl[0] = bf2f(b.x & 0xffffu); wl[1] = bf2f(b.x >> 16);
      wl[2] = bf2f(b.y & 0xffffu); wl[3] = bf2f(b.y >> 16);
      wl[4] = bf2f(b.z & 0xffffu); wl[5] = bf2f(b.z >> 16);
      wl[6] = bf2f(b.w & 0xffffu); wl[7] = bf2f(b.w >> 16);
    }

    float4 u0 = *(const float4*)(ubi + c),  u1 = *(const float4*)(ubi + c + 4);
    float4 l0 = *(const float4*)(lbi + c),  l1 = *(const float4*)(lbi + c + 4);
    float4 p0 = *(const float4*)(bupi + c), p1 = *(const float4*)(bupi + c + 4);
    float4 n0 = *(const float4*)(bloi + c), n1 = *(const float4*)(bloi + c + 4);
    float uu[8] = {u0.x, u0.y, u0.z, u0.w, u1.x, u1.y, u1.z, u1.w};
    float ll[8] = {l0.x, l0.y, l0.z, l0.w, l1.x, l1.y, l1.z, l1.w};
    float pp[8] = {p0.x, p0.y, p0.z, p0.w, p1.x, p1.y, p1.z, p1.w};
    float nn[8] = {n0.x, n0.y, n0.z, n0.w, n1.x, n1.y, n1.z, n1.w};

    float su_c = 0.f, su_b = 0.f, sl_c = 0.f, sl_b = 0.f;
    #pragma unroll
    for (int j = 0; j < 8; ++j) {
      su_c += wu[j] * (wu[j] >= 0.f ? uu[j] : ll[j]);
      su_b += wu[j] * (wu[j] >= 0.f ? pp[j] : nn[j]);
      sl_c += wl[j] * (wl[j] >= 0.f ? ll[j] : uu[j]);
      sl_b += wl[j] * (wl[j] >= 0.f ? nn[j] : pp[j]);
    }

    #pragma unroll
    for (int off = 32; off; off >>= 1) {
      su_c += __shfl_down(su_c, off);
      su_b += __shfl_down(su_b, off);
      sl_c += __shfl_down(sl_c, off);
      sl_b += __shfl_down(sl_b, off);
    }
    int wave = t >> 6;
    if ((t & 63) == 0) {
      red[0][wave] = su_c; red[1][wave] = su_b;
      red[2][wave] = sl_c; red[3][wave] = sl_b;
    }
    __syncthreads();
    if (t == 0) {
      float a = red[0][0] + red[0][1] + red[0][2] + red[0][3];
      float b = red[1][0] + red[1][1] + red[1][2] + red[1][3];
      float cc = red[2][0] + red[2][1] + red[2][2] + red[2][3];
      float d = red[3][0] + red[3][1] + red[3][2] + red[3][3];
      float bu_old = bu[r], bl_old = bl[r];
      best[r]     = fminf(best[r],     a + bu_old);
      best[D + r] = fmaxf(best[D + r], cc + bl_old);
      if (update_bias) {
        bu[r] = b + bu_old;
        bl[r] = d + bl_old;
      }
    }
  } else {
    const int bx = blockIdx.x - 2048;
    const int k0 = (bx >> 5) * 64, c0 = (bx & 31) * 64;
    const int tx = t & 15, ty = t >> 4;
    #pragma unroll
    for (int r = 0; r < 4; ++r) {
      int kk = ty + r * 16;
      size_t g = (size_t)(k0 + kk) * D + c0 + tx * 4;
      float4 up = *(const float4*)(Wup + g);
      float4 lo = *(const float4*)(Wlo + g);
      sS[kk][tx * 4 + 0] = f2bf((up.x + lo.x) * 0.5f);
      sS[kk][tx * 4 + 1] = f2bf((up.y + lo.y) * 0.5f);
      sS[kk][tx * 4 + 2] = f2bf((up.z + lo.z) * 0.5f);
      sS[kk][tx * 4 + 3] = f2bf((up.w + lo.w) * 0.5f);
      sD[kk][tx * 4 + 0] = f2bf((up.x - lo.x) * 0.5f);
      sD[kk][tx * 4 + 1] = f2bf((up.y - lo.y) * 0.5f);
      sD[kk][tx * 4 + 2] = f2bf((up.z - lo.z) * 0.5f);
      sD[kk][tx * 4 + 3] = f2bf((up.w - lo.w) * 0.5f);
    }
    __syncthreads();
    #pragma unroll
    for (int r = 0; r < 4; ++r) {
      int cc = ty + r * 16;
      int kq = tx * 4;
      unsigned a0 = sS[kq + 0][cc] | ((unsigned)sS[kq + 1][cc] << 16);
      unsigned a1 = sS[kq + 2][cc] | ((unsigned)sS[kq + 3][cc] << 16);
      *(uint2*)(BsT + (size_t)(c0 + cc) * D + k0 + kq) = make_uint2(a0, a1);
      a0 = sD[kq + 0][cc] | ((unsigned)sD[kq + 1][cc] << 16);
      a1 = sD[kq + 2][cc] | ((unsigned)sD[kq + 3][cc] << 16);
      *(uint2*)(BdT + (size_t)(c0 + cc) * D + k0 + kq) = make_uint2(a0, a1);
    }
  }
}

// ---------------------------------------------------------------------------
// Fused dual GEMM — K-split wave pairs, both outputs per wave (bf16 out).
// Each wave (h = wid>>2, w2 = wid&3) computes BOTH Cu and Cl for its 64x64
// position tile (wr=w2>>1, wc=w2&1) over K-half h of each BK=64 tile:
//   accU += awU@bs + |awU|@bd ;  accL += awL@bs + (-|awL|)@bd
// (-|a| = a | 0x8000, one OR). B fragments are read ONCE per position
// (R13 read them twice across the grp split): 128 ds_read/tile vs 192.
// Wave pair (w, w+4) reduces partials through LDS (4 x 32KB) at the end.
// Staging/swizzle/XCD mapping identical to R8/R13 (verified).
// ---------------------------------------------------------------------------
__global__ __launch_bounds__(512, 2) void gemm_fused(
    const unsigned short* __restrict__ w16U,
    const unsigned short* __restrict__ w16L,
    const unsigned short* __restrict__ BsT,
    const unsigned short* __restrict__ BdT,
    unsigned short* __restrict__ Cu, unsigned short* __restrict__ Cl) {
  extern __shared__ unsigned char lds[];

  const int bid = blockIdx.x;
  const int vid = (bid & 7) * 32 + (bid >> 3);
  const int row0 = (vid >> 4) * 128, col0 = (vid & 15) * 128;

  const int tid = threadIdx.x;
  const int lane = tid & 63, wid = tid >> 6;
  const int h = wid >> 2;              // K-half of each BK=64 tile
  const int w2 = wid & 3;
  const int wr = w2 >> 1, wc = w2 & 1; // 64x64 position tile
  const int l31 = lane & 31, kh = lane >> 5;

  // staging (identical to R8): stream tile 16KB = 16 chunks of 1KB
  // (8 rows x 128B); wave wid stages chunks {wid, wid+8}.
  const int srow8 = lane >> 3;
  const int slot  = lane & 7;
  int rowc[2], swel[2];
  #pragma unroll
  for (int c = 0; c < 2; ++c) {
    rowc[c] = (wid + c * 8) * 8 + srow8;
    swel[c] = (slot ^ (rowc[c] & 7)) * 8;
  }
  const unsigned short* gAU[2]; const unsigned short* gAL[2];
  const unsigned short* gBs[2]; const unsigned short* gBd[2];
  #pragma unroll
  for (int c = 0; c < 2; ++c) {
    gAU[c] = w16U + (size_t)(row0 + rowc[c]) * D + swel[c];
    gAL[c] = w16L + (size_t)(row0 + rowc[c]) * D + swel[c];
    gBs[c] = BsT + (size_t)(col0 + rowc[c]) * D + swel[c];
    gBd[c] = BdT + (size_t)(col0 + rowc[c]) * D + swel[c];
  }

  f32x16 acc[2][2][2] = {};   // [u/l][mb][nb]

  // fragment offsets: slot index = (h*2 + ksl)*2 + kh, XOR row&7 swizzle
  int aoff[2][2], boff[2][2];  // [mb][ksl], [nb][ksl]
  #pragma unroll
  for (int mb = 0; mb < 2; ++mb) {
    int ar = wr * 64 + mb * 32 + l31;
    #pragma unroll
    for (int ksl = 0; ksl < 2; ++ksl)
      aoff[mb][ksl] = ar * 128 + ((((h * 2 + ksl) * 2 + kh) ^ (ar & 7)) * 16);
  }
  #pragma unroll
  for (int nb = 0; nb < 2; ++nb) {
    int bc = wc * 64 + nb * 32 + l31;
    #pragma unroll
    for (int ksl = 0; ksl < 2; ++ksl)
      boff[nb][ksl] = bc * 128 + ((((h * 2 + ksl) * 2 + kh) ^ (bc & 7)) * 16);
  }

  #define STAGE(curb, kt)                                                          \
    do {                                                                           \
      unsigned bb = (unsigned)(curb) * 65536u;                                     \
      _Pragma("unroll")                                                            \
      for (int c = 0; c < 2; ++c) {                                                \
        unsigned dst = bb + (unsigned)(wid + c * 8) * 1024u;                       \
        __builtin_amdgcn_global_load_lds((const GLOBAL_AS unsigned*)(gAU[c] + (kt)),\
            (LDS_AS unsigned*)(lds + 0 + dst), 16, 0, 0);                          \
        __builtin_amdgcn_global_load_lds((const GLOBAL_AS unsigned*)(gAL[c] + (kt)),\
            (LDS_AS unsigned*)(lds + 16384 + dst), 16, 0, 0);                      \
        __builtin_amdgcn_global_load_lds((const GLOBAL_AS unsigned*)(gBs[c] + (kt)),\
            (LDS_AS unsigned*)(lds + 32768 + dst), 16, 0, 0);                      \
        __builtin_amdgcn_global_load_lds((const GLOBAL_AS unsigned*)(gBd[c] + (kt)),\
            (LDS_AS unsigned*)(lds + 49152 + dst), 16, 0, 0);                      \
      }                                                                            \
    } while (0)

  STAGE(0, 0);
  __syncthreads();

  int cur = 0;
  for (int t = 0; t < 32; ++t) {
    if (t < 31) STAGE(cur ^ 1, (t + 1) * 64);

    const unsigned char* Ub = lds + 0 + cur * 65536;
    const unsigned char* Lb = lds + 16384 + cur * 65536;
    const unsigned char* Sb = lds + 32768 + cur * 65536;
    const unsigned char* Db = lds + 49152 + cur * 65536;

    #pragma unroll
    for (int ksl = 0; ksl < 2; ++ksl) {
      bf16x8 au0 = *(const bf16x8*)(Ub + aoff[0][ksl]);
      bf16x8 au1 = *(const bf16x8*)(Ub + aoff[1][ksl]);
      bf16x8 al0 = *(const bf16x8*)(Lb + aoff[0][ksl]);
      bf16x8 al1 = *(const bf16x8*)(Lb + aoff[1][ksl]);
      bf16x8 bs0 = *(const bf16x8*)(Sb + boff[0][ksl]);
      bf16x8 bs1 = *(const bf16x8*)(Sb + boff[1][ksl]);
      bf16x8 bd0 = *(const bf16x8*)(Db + boff[0][ksl]);
      bf16x8 bd1 = *(const bf16x8*)(Db + boff[1][ksl]);

      bf16x8 vu0 = au0 & (short)0x7fff;   //  |A_U|
      bf16x8 vu1 = au1 & (short)0x7fff;
      bf16x8 vl0 = al0 | (short)0x8000;   // -|A_L|
      bf16x8 vl1 = al1 | (short)0x8000;

      acc[0][0][0] = __builtin_amdgcn_mfma_f32_32x32x16_bf16(au0, bs0, acc[0][0][0], 0, 0, 0);
      acc[0][0][0] = __builtin_amdgcn_mfma_f32_32x32x16_bf16(vu0, bd0, acc[0][0][0], 0, 0, 0);
      acc[0][0][1] = __builtin_amdgcn_mfma_f32_32x32x16_bf16(au0, bs1, acc[0][0][1], 0, 0, 0);
      acc[0][0][1] = __builtin_amdgcn_mfma_f32_32x32x16_bf16(vu0, bd1, acc[0][0][1], 0, 0, 0);
      acc[0][1][0] = __builtin_amdgcn_mfma_f32_32x32x16_bf16(au1, bs0, acc[0][1][0], 0, 0, 0);
      acc[0][1][0] = __builtin_amdgcn_mfma_f32_32x32x16_bf16(vu1, bd0, acc[0][1][0], 0, 0, 0);
      acc[0][1][1] = __builtin_amdgcn_mfma_f32_32x32x16_bf16(au1, bs1, acc[0][1][1], 0, 0, 0);
      acc[0][1][1] = __builtin_amdgcn_mfma_f32_32x32x16_bf16(vu1, bd1, acc[0][1][1], 0, 0, 0);
      acc[1][0][0] = __builtin_amdgcn_mfma_f32_32x32x16_bf16(al0, bs0, acc[1][0][0], 0, 0, 0);
      acc[1][0][0] = __builtin_amdgcn_mfma_f32_32x32x16_bf16(vl0, bd0, acc[1][0][0], 0, 0, 0);
      acc[1][0][1] = __builtin_amdgcn_mfma_f32_32x32x16_bf16(al0, bs1, acc[1][0][1], 0, 0, 0);
      acc[1][0][1] = __builtin_amdgcn_mfma_f32_32x32x16_bf16(vl0, bd1, acc[1][0][1], 0, 0, 0);
      acc[1][1][0] = __builtin_amdgcn_mfma_f32_32x32x16_bf16(al1, bs0, acc[1][1][0], 0, 0, 0);
      acc[1][1][0] = __builtin_amdgcn_mfma_f32_32x32x16_bf16(vl1, bd0, acc[1][1][0], 0, 0, 0);
      acc[1][1][1] = __builtin_amdgcn_mfma_f32_32x32x16_bf16(al1, bs1, acc[1][1][1], 0, 0, 0);
      acc[1][1][1] = __builtin_amdgcn_mfma_f32_32x32x16_bf16(vl1, bd1, acc[1][1][1], 0, 0, 0);
    }

    __syncthreads();
    cur ^= 1;
  }
  #undef STAGE

  // ---- wave-pair reduction: h=1 waves dump partials to LDS (4 x 32KB) ----
  const unsigned rbase = (unsigned)w2 * 32768u + (unsigned)lane * 64u;
  if (h == 1) {
    #pragma unroll
    for (int u = 0; u < 2; ++u)
      #pragma unroll
      for (int mb = 0; mb < 2; ++mb)
        #pragma unroll
        for (int nb = 0; nb < 2; ++nb)
          *(f32x16*)(lds + rbase + (unsigned)(((u * 2 + mb) * 2 + nb)) * 4096u)
              = acc[u][mb][nb];
  }
  __syncthreads();
  if (h == 0) {
    #pragma unroll
    for (int u = 0; u < 2; ++u) {
      unsigned short* C = u ? Cl : Cu;
      #pragma unroll
      for (int mb = 0; mb < 2; ++mb)
        #pragma unroll
        for (int nb = 0; nb < 2; ++nb) {
          f32x16 p = *(const f32x16*)(lds + rbase +
                       (unsigned)(((u * 2 + mb) * 2 + nb)) * 4096u);
          f32x16 s = acc[u][mb][nb] + p;
          const int colg = col0 + wc * 64 + nb * 32 + l31;
          const int rowb = row0 + wr * 64 + mb * 32 + kh * 4;
          #pragma unroll
          for (int g = 0; g < 4; ++g)
            #pragma unroll
            for (int j = 0; j < 4; ++j)
              C[(size_t)(rowb + g * 8 + j) * D + colg] = f2bf(s[g * 4 + j]);
        }
    }
  }
}

// ---------------------------------------------------------------------------
extern "C" void kernel_launch(void* const* d_in, const int* in_sizes, int n_in,
                              void* d_out, int out_size, void* d_ws, size_t ws_size,
                              hipStream_t stream) {
  const float* W_upper = (const float*)d_in[0];
  const float* W_lower = (const float*)d_in[1];
  const float* b_upper = (const float*)d_in[2];
  const float* b_lower = (const float*)d_in[3];
  const float* ub      = (const float*)d_in[4];
  const float* lb      = (const float*)d_in[5];
  float* out = (float*)d_out;

  // workspace (48MB + 16KB): bf16 A ping-pong pairs, BsT/BdT, bias vecs
  unsigned short* aU[2]; unsigned short* aL[2];
  aU[0] = (unsigned short*)d_ws;
  aL[0] = aU[0] + DD;
  aU[1] = aL[0] + DD;
  aL[1] = aU[1] + DD;
  unsigned short* BsT = aL[1] + DD;
  unsigned short* BdT = BsT + DD;
  float* bu = (float*)(BdT + DD);
  float* bl = bu + D;

  static_cast<void>(hipFuncSetAttribute(
      (const void*)gemm_fused, hipFuncAttributeMaxDynamicSharedMemorySize, 131072));

  init_vecs<<<(D + 255) / 256, 256, 0, stream>>>(
      b_upper + 5 * D, b_lower + 5 * D, ub + 5 * D, lb + 5 * D, bu, bl, out);

  int cur = 0;
  for (int i = 4; i >= 0; --i) {
    const int first = (i == 4);
    prep<<<3072, 256, 0, stream>>>(
        W_upper + 5 * DD, W_lower + 5 * DD,
        aU[cur], aL[cur],
        ub + (size_t)i * D, lb + (size_t)i * D,
        b_upper + (size_t)i * D, b_lower + (size_t)i * D,
        bu, bl, out,
        aU[cur], aL[cur],
        W_upper + (size_t)i * DD, W_lower + (size_t)i * DD,
        BsT, BdT, 1, first);
    gemm_fused<<<256, 512, 131072, stream>>>(aU[cur], aL[cur], BsT, BdT,
                                             aU[cur ^ 1], aL[cur ^ 1]);
    cur ^= 1;
  }
  // final concretization against input-layer bounds (layer 0)
  prep<<<2048, 256, 0, stream>>>(
      (const float*)nullptr, (const float*)nullptr,
      aU[cur], aL[cur],
      ub, lb, b_upper, b_lower, bu, bl, out,
      (unsigned short*)nullptr, (unsigned short*)nullptr,
      (const float*)nullptr, (const float*)nullptr,
      (unsigned short*)nullptr, (unsigned short*)nullptr, 0, 0);
}